// Round 1
// baseline (669.034 us; speedup 1.0000x reference)
//
#include <hip/hip_runtime.h>
#include <hip/hip_bf16.h>

#define E_EDGES 120000
#define NUM_NODES 12000

typedef __attribute__((ext_vector_type(8))) short bfrag;          // 8 bf16
typedef __attribute__((ext_vector_type(8))) unsigned short ushort8;
typedef __attribute__((ext_vector_type(4))) float f32x4;

#define INV_SQRT3 0.57735026918962576f
#define SQRT2_C   1.41421356237309515f
#define N_0E_C    0.14433756729740643f   /* 1/sqrt(48) */
#define NV_C      0.14433756729740643f   /* sqrt(3/48)*1/sqrt(3) = 1/sqrt(48) */
#define WSCALE    0.08838834764831845f   /* 1/sqrt(128) */

__device__ __forceinline__ unsigned short f2bf(float f) {
    union { float f; unsigned int u; } v; v.f = f;
    unsigned int r = v.u + 0x7fffu + ((v.u >> 16) & 1u);
    return (unsigned short)(r >> 16);
}

__device__ __forceinline__ ushort8 pack8(f32x4 a, f32x4 b) {
    ushort8 o;
    o[0] = f2bf(a.x); o[1] = f2bf(a.y); o[2] = f2bf(a.z); o[3] = f2bf(a.w);
    o[4] = f2bf(b.x); o[5] = f2bf(b.y); o[6] = f2bf(b.z); o[7] = f2bf(b.w);
    return o;
}

// ---- Kernel: transpose + scale w_emb (128 x 3072, row-major) -> Bt[n][k] bf16
__global__ void k_wt(const float* __restrict__ w_emb, unsigned short* __restrict__ Bt) {
    int i = blockIdx.x * 256 + threadIdx.x;          // i = n*128 + c
    if (i >= 3072 * 128) return;
    int n = i >> 7, c = i & 127;
    Bt[i] = f2bf(w_emb[c * 3072 + n] * WSCALE);
}

// ---- Kernel: per-edge prep: emb bf16 [E][128], rT fp32 [128][E]
__global__ void k_prep(const float* __restrict__ x, const float* __restrict__ edge_attr,
                       const float* __restrict__ Yij, const int* __restrict__ edge_index,
                       unsigned short* __restrict__ emb, float* __restrict__ rT) {
    int e = blockIdx.x * 256 + threadIdx.x;
    if (e >= E_EDGES) return;
    int dst = edge_index[e];
    int src = edge_index[E_EDGES + e];
    f32x4 y = *(const f32x4*)(Yij + 4 * (long)e);
    float y0 = y.x, y1a = y.y, y1b = y.z, y1c = y.w;
    const float* xd = x + (long)dst * 80;
    const float* xs = x + (long)src * 80;
    const float* ea = edge_attr + (long)e * 64;

    ushort8* embp = (ushort8*)(emb + (long)e * 128);

    float xsv[80];
#pragma unroll
    for (int i = 0; i < 80; i += 4) {
        f32x4 v = *(const f32x4*)(xs + i);
        xsv[i] = v.x; xsv[i + 1] = v.y; xsv[i + 2] = v.z; xsv[i + 3] = v.w;
    }
    // emb[0..31] = xs[dst]
#pragma unroll
    for (int cb = 0; cb < 4; ++cb) {
        f32x4 a = *(const f32x4*)(xd + cb * 8);
        f32x4 b = *(const f32x4*)(xd + cb * 8 + 4);
        embp[cb] = pack8(a, b);
    }
    // emb[32..63] = xs[src]
#pragma unroll
    for (int cb = 0; cb < 4; ++cb) {
        f32x4 a, b;
        a.x = xsv[cb * 8 + 0]; a.y = xsv[cb * 8 + 1]; a.z = xsv[cb * 8 + 2]; a.w = xsv[cb * 8 + 3];
        b.x = xsv[cb * 8 + 4]; b.y = xsv[cb * 8 + 5]; b.z = xsv[cb * 8 + 6]; b.w = xsv[cb * 8 + 7];
        embp[4 + cb] = pack8(a, b);
    }
    // emb[64..127] = edge_attr
#pragma unroll
    for (int cb = 0; cb < 8; ++cb) {
        f32x4 a = *(const f32x4*)(ea + cb * 8);
        f32x4 b = *(const f32x4*)(ea + cb * 8 + 4);
        embp[8 + cb] = pack8(a, b);
    }
    // rT rows (coalesced across lanes):
    //  [0..31]   sy0 = xs_src * y0
    //  [32..47]  vdot = (xv_src . y1) * INV_SQRT3
    //  [48..79]  x1s
    //  [80..127] xvy0[u*3+k] = xv[u][k] * y0
#pragma unroll
    for (int u = 0; u < 32; ++u) rT[(long)u * E_EDGES + e] = xsv[u] * y0;
#pragma unroll
    for (int u = 0; u < 16; ++u)
        rT[(long)(32 + u) * E_EDGES + e] =
            (xsv[32 + 3 * u] * y1a + xsv[33 + 3 * u] * y1b + xsv[34 + 3 * u] * y1c) * INV_SQRT3;
#pragma unroll
    for (int u = 0; u < 32; ++u) rT[(long)(48 + u) * E_EDGES + e] = xsv[u];
#pragma unroll
    for (int j = 0; j < 48; ++j) rT[(long)(80 + j) * E_EDGES + e] = xsv[32 + j] * y0;
}

// ---- Kernel: fused GEMM (emb @ Bt^T) + u-contraction + atomic scatter to nodes
__global__ __launch_bounds__(256) void k_gemm(
    const unsigned short* __restrict__ emb, const unsigned short* __restrict__ Bt,
    const float* __restrict__ rT, const int* __restrict__ edge_index,
    const float* __restrict__ Yij, float* __restrict__ summed, float* __restrict__ cnt) {
    const int lane = threadIdx.x & 63;
    const int wave = threadIdx.x >> 6;
    const long e0 = ((long)blockIdx.x * 4 + wave) * 32;   // 32 edges per wave
    if (e0 >= E_EDGES) return;
    const int col = lane & 15, quad = lane >> 4;

    // A fragments, register-resident for the whole N sweep (2 slabs x 4 k-blocks)
    bfrag A[2][4];
#pragma unroll
    for (int s = 0; s < 2; ++s) {
        const unsigned short* ap = emb + (e0 + s * 16 + col) * 128 + quad * 8;
#pragma unroll
        for (int kb = 0; kb < 4; ++kb) A[s][kb] = *(const bfrag*)(ap + kb * 32);
    }

    f32x4 z = {0.f, 0.f, 0.f, 0.f};
    f32x4 acc_s0[2] = {z, z}, acc_s1[2] = {z, z}, acc_g[2] = {z, z}, acc_t5[2] = {z, z};
    f32x4 acc_v[2][3] = {{z, z, z}, {z, z, z}};

    const unsigned short* bp = Bt + col * 128 + quad * 8;
    const float* rbase = rT + e0 + quad * 4;

    auto mm = [&](int t, f32x4& c0, f32x4& c1) {
        const unsigned short* b = bp + (long)t * 2048;
        bfrag B0 = *(const bfrag*)(b);
        bfrag B1 = *(const bfrag*)(b + 32);
        bfrag B2 = *(const bfrag*)(b + 64);
        bfrag B3 = *(const bfrag*)(b + 96);
        c0 = z; c1 = z;
        c0 = __builtin_amdgcn_mfma_f32_16x16x32_bf16(A[0][0], B0, c0, 0, 0, 0);
        c1 = __builtin_amdgcn_mfma_f32_16x16x32_bf16(A[1][0], B0, c1, 0, 0, 0);
        c0 = __builtin_amdgcn_mfma_f32_16x16x32_bf16(A[0][1], B1, c0, 0, 0, 0);
        c1 = __builtin_amdgcn_mfma_f32_16x16x32_bf16(A[1][1], B1, c1, 0, 0, 0);
        c0 = __builtin_amdgcn_mfma_f32_16x16x32_bf16(A[0][2], B2, c0, 0, 0, 0);
        c1 = __builtin_amdgcn_mfma_f32_16x16x32_bf16(A[1][2], B2, c1, 0, 0, 0);
        c0 = __builtin_amdgcn_mfma_f32_16x16x32_bf16(A[0][3], B3, c0, 0, 0, 0);
        c1 = __builtin_amdgcn_mfma_f32_16x16x32_bf16(A[1][3], B3, c1, 0, 0, 0);
    };

    // W1: tiles 0..63, u = t/2, w = col + 16*(t&1), weight sy0[u] -> out_s
#pragma unroll 2
    for (int u = 0; u < 32; ++u) {
        f32x4 c0a, c1a, c0b, c1b;
        mm(2 * u, c0a, c1a);
        mm(2 * u + 1, c0b, c1b);
        const float* rw = rbase + (long)u * E_EDGES;
        f32x4 w0 = *(const f32x4*)(rw);
        f32x4 w1 = *(const f32x4*)(rw + 16);
        acc_s0[0] += c0a * w0; acc_s1[0] += c0b * w0;
        acc_s0[1] += c1a * w1; acc_s1[1] += c1b * w1;
    }
    // W2: tiles 64..95, u = t-64, weight sy0[u] -> out_g
#pragma unroll 2
    for (int u = 0; u < 32; ++u) {
        f32x4 c0, c1; mm(64 + u, c0, c1);
        const float* rw = rbase + (long)u * E_EDGES;
        acc_g[0] += c0 * *(const f32x4*)(rw);
        acc_g[1] += c1 * *(const f32x4*)(rw + 16);
    }
    // W3: tiles 96..127, u = (t-96)/2, weight vdot[u]=r[32+u] -> out_s
#pragma unroll 2
    for (int u = 0; u < 16; ++u) {
        f32x4 c0a, c1a, c0b, c1b;
        mm(96 + 2 * u, c0a, c1a);
        mm(97 + 2 * u, c0b, c1b);
        const float* rw = rbase + (long)(32 + u) * E_EDGES;
        f32x4 w0 = *(const f32x4*)(rw);
        f32x4 w1 = *(const f32x4*)(rw + 16);
        acc_s0[0] += c0a * w0; acc_s1[0] += c0b * w0;
        acc_s0[1] += c1a * w1; acc_s1[1] += c1b * w1;
    }
    // W4: tiles 128..143, weight vdot[u] -> out_g
#pragma unroll 2
    for (int u = 0; u < 16; ++u) {
        f32x4 c0, c1; mm(128 + u, c0, c1);
        const float* rw = rbase + (long)(32 + u) * E_EDGES;
        acc_g[0] += c0 * *(const f32x4*)(rw);
        acc_g[1] += c1 * *(const f32x4*)(rw + 16);
    }
    // W5: tiles 144..175, weight x1s[u]=r[48+u] -> t5
#pragma unroll 2
    for (int u = 0; u < 32; ++u) {
        f32x4 c0, c1; mm(144 + u, c0, c1);
        const float* rw = rbase + (long)(48 + u) * E_EDGES;
        acc_t5[0] += c0 * *(const f32x4*)(rw);
        acc_t5[1] += c1 * *(const f32x4*)(rw + 16);
    }
    // W6: tiles 176..191, weights xvy0[u][k]=r[80+3u+k] -> out_v[.][k]
#pragma unroll 2
    for (int u = 0; u < 16; ++u) {
        f32x4 c0, c1; mm(176 + u, c0, c1);
        const float* rw = rbase + (long)(80 + 3 * u) * E_EDGES;
#pragma unroll
        for (int k = 0; k < 3; ++k) {
            f32x4 w0 = *(const f32x4*)(rw + (long)k * E_EDGES);
            f32x4 w1 = *(const f32x4*)(rw + (long)k * E_EDGES + 16);
            acc_v[0][k] += c0 * w0;
            acc_v[1][k] += c1 * w1;
        }
    }

    // Epilogue: scale + atomic scatter into summed[node][96], cnt[node]
#pragma unroll
    for (int s = 0; s < 2; ++s) {
        long eb = e0 + s * 16 + quad * 4;
#pragma unroll
        for (int r = 0; r < 4; ++r) {
            long e = eb + r;
            int d = edge_index[e];
            float* base = summed + (long)d * 96;
            float y1a = Yij[4 * e + 1], y1b = Yij[4 * e + 2], y1c = Yij[4 * e + 3];
            atomicAdd(base + col,       N_0E_C * acc_s0[s][r]);
            atomicAdd(base + col + 16,  N_0E_C * acc_s1[s][r]);
            atomicAdd(base + 32 + col,  N_0E_C * acc_g[s][r]);
            float t5 = acc_t5[s][r];
            atomicAdd(base + 48 + col * 3 + 0, NV_C * (t5 * y1a + acc_v[s][0][r]));
            atomicAdd(base + 48 + col * 3 + 1, NV_C * (t5 * y1b + acc_v[s][1][r]));
            atomicAdd(base + 48 + col * 3 + 2, NV_C * (t5 * y1c + acc_v[s][2][r]));
            if (col == 0) atomicAdd(cnt + d, 1.0f);
        }
    }
}

// ---- Kernel: mean, relu-gate, residual
__global__ void k_final(const float* __restrict__ x, const float* __restrict__ summed,
                        const float* __restrict__ cnt, float* __restrict__ out) {
    int tid = blockIdx.x * 256 + threadIdx.x;
    if (tid >= NUM_NODES * 80) return;
    int n = tid / 80, c = tid % 80;
    float m = fmaxf(cnt[n], 1.0f);
    float inv = 1.0f / m;
    float val;
    if (c < 32) {
        val = SQRT2_C * fmaxf(summed[(long)n * 96 + c] * inv, 0.0f);
    } else {
        int j = c - 32;
        int w = j / 3;
        float g = SQRT2_C * fmaxf(summed[(long)n * 96 + 32 + w] * inv, 0.0f);
        val = summed[(long)n * 96 + 48 + j] * inv * g;
    }
    out[tid] = x[tid] + val;
}

extern "C" void kernel_launch(void* const* d_in, const int* in_sizes, int n_in,
                              void* d_out, int out_size, void* d_ws, size_t ws_size,
                              hipStream_t stream) {
    const float* x         = (const float*)d_in[0];
    const float* edge_attr = (const float*)d_in[1];
    const float* Yij       = (const float*)d_in[2];
    const int*   edge_index= (const int*)d_in[3];
    const float* w_emb     = (const float*)d_in[4];
    float* out = (float*)d_out;

    char* ws = (char*)d_ws;
    size_t off = 0;
    unsigned short* emb = (unsigned short*)(ws + off); off += (size_t)E_EDGES * 128 * 2;   // 30.72 MB
    unsigned short* Bt  = (unsigned short*)(ws + off); off += (size_t)3072 * 128 * 2;      // 0.79 MB
    off = (off + 255) & ~(size_t)255;
    float* rT     = (float*)(ws + off); off += (size_t)128 * E_EDGES * 4;                  // 61.44 MB
    size_t zoff = off;
    float* summed = (float*)(ws + off); off += (size_t)NUM_NODES * 96 * 4;                 // 4.61 MB
    float* cnt    = (float*)(ws + off); off += (size_t)NUM_NODES * 4;

    hipMemsetAsync(ws + zoff, 0, (size_t)NUM_NODES * 97 * 4, stream);
    k_wt  <<<(3072 * 128 + 255) / 256, 256, 0, stream>>>(w_emb, Bt);
    k_prep<<<(E_EDGES + 255) / 256, 256, 0, stream>>>(x, edge_attr, Yij, edge_index, emb, rT);
    k_gemm<<<(E_EDGES + 127) / 128, 256, 0, stream>>>(emb, Bt, rT, edge_index, Yij, summed, cnt);
    k_final<<<(NUM_NODES * 80 + 255) / 256, 256, 0, stream>>>(x, summed, cnt, out);
}